// Round 5
// baseline (250.790 us; speedup 1.0000x reference)
//
#include <hip/hip_runtime.h>
#include <hip/hip_bf16.h>

#define B_   32
#define L_   2048
#define CIN  256
#define HID  512
#define TL   32
#define NLT  (L_ / TL)   // 64 l-tiles of 32 rows per batch

typedef __bf16 bf16_t;
typedef __bf16 bf16x8 __attribute__((ext_vector_type(8)));
typedef __bf16 bf16x4 __attribute__((ext_vector_type(4)));
typedef float  f32x4  __attribute__((ext_vector_type(4)));

// LDS map (64 KB): A(x)@0(16K) A(y)@16K(16K) alias H(x)@0(32K) H(y)@32K(32K)
#define AX_OFF 0u
#define AY_OFF 16384u
#define HX_OFF 0u
#define HY_OFF 32768u

__device__ __forceinline__ float fast_tanh(float v) {
    float x = fminf(fmaxf(v, -9.0f), 9.0f);
    float e = exp2f(x * 2.885390081777927f);           // e^{2x}
    return (e - 1.0f) * __builtin_amdgcn_rcpf(e + 1.0f);
}

// ---------------------------------------------------------------------------
// Kernel 1: cast weights fp32 -> bf16 into workspace
// ---------------------------------------------------------------------------
__global__ void cast_weights_kernel(const float* __restrict__ W1, const float* __restrict__ W2,
                                    bf16_t* __restrict__ W1b, bf16_t* __restrict__ W2b)
{
    int i = blockIdx.x * blockDim.x + threadIdx.x;
    if (i < HID * CIN) W1b[i] = (bf16_t)W1[i];
    if (i < HID * HID) W2b[i] = (bf16_t)W2[i];
}

// ---------------------------------------------------------------------------
// Kernel 2: fused project(x)+project(y), tanh*tanh, partial row-reduction.
// Block = 512 threads (8 waves) on one (batch, 32-row tile). Wave w owns
// cols [w*64, w*64+64) (j=0..3), rows i=0..1. x,y pipelines share each
// weight fragment. LDS 64 KB -> 2 blocks/CU: one block's HBM stage phase
// overlaps the other block's GEMM phases (cross-block TLP).
// 128 total regs/wave (64 arch + 64 AGPR acc) * 16 waves = full 2048 budget.
// ---------------------------------------------------------------------------
__global__ __launch_bounds__(512, 4)
void fused_proj_kernel(const float* __restrict__ x, const float* __restrict__ y,
                       const bf16_t* __restrict__ W1b, const float* __restrict__ b1,
                       const bf16_t* __restrict__ W2b, const float* __restrict__ b2,
                       float* __restrict__ partial)
{
    __shared__ char U[65536];            // 64 KB

    const int tid  = threadIdx.x;
    const int lane = tid & 63;
    const int wv   = tid >> 6;           // wave 0..7
    const int l15  = lane & 15;
    const int l4   = lane >> 4;
    const int blk  = blockIdx.x;
    const int b    = blk >> 6;           // batch
    const int lt   = blk & 63;           // 32-row l-tile
    const int col0 = wv * 64;            // this wave's output-col base

    const float* xrows = x + ((size_t)(b * L_) + (size_t)lt * TL) * CIN;
    const float* yrows = y + ((size_t)(b * L_) + (size_t)lt * TL) * CIN;

    float bias1[4], bias2[4];
#pragma unroll
    for (int j = 0; j < 4; ++j) {
        bias1[j] = b1[col0 + j * 16 + l15];
        bias2[j] = b2[col0 + j * 16 + l15];
    }

    // --- stage [32 x CIN] fp32 x-tile and y-tile -> bf16 LDS (swizzled).
    // threads 0-255 stage x, 256-511 stage y; 2 rounds of 4 float4 to keep
    // transient register pressure at 16 VGPRs.
    {
        const int p   = tid >> 8;
        const int t8  = tid & 255;
        const int r   = t8 >> 3;         // 32 rows, 8 threads/row
        const int q   = t8 & 7;
        const float* src = (p ? yrows : xrows) + (size_t)r * CIN;
        char* rowp = U + (p ? AY_OFF : AX_OFF) + r * (CIN * 2);
        const unsigned swz = (unsigned)((r & 15) << 4);
#pragma unroll
        for (int half = 0; half < 2; ++half) {
            float4 v[4];
#pragma unroll
            for (int c = 0; c < 4; ++c)
                v[c] = reinterpret_cast<const float4*>(src)[q + 8 * (half * 4 + c)];
#pragma unroll
            for (int c = 0; c < 4; ++c) {
                const int f = q + 8 * (half * 4 + c);
                bf16x4 h;
                h[0] = (bf16_t)v[c].x; h[1] = (bf16_t)v[c].y;
                h[2] = (bf16_t)v[c].z; h[3] = (bf16_t)v[c].w;
                *reinterpret_cast<bf16x4*>(rowp + (((unsigned)(8 * f)) ^ swz)) = h;
            }
        }
    }
    __syncthreads();                     // A(x), A(y) ready

    // Precomputed swizzled LDS base offsets; per-kk address is base ^ (kk*64)
    // (valid: kk*64 stays below the row-stride bit and the swizzle XOR
    // commutes with the disjoint-bit add).
    unsigned aoff[2], hoff[2];
#pragma unroll
    for (int i = 0; i < 2; ++i) {
        const int r = i * 16 + l15;
        const unsigned swz = (unsigned)((r & 15) << 4);
        aoff[i] = (unsigned)(r * (CIN * 2)) + (((unsigned)(l4 * 16)) ^ swz);
        hoff[i] = (unsigned)(r * (HID * 2)) + (((unsigned)(l4 * 16)) ^ swz);
    }

    f32x4 accx[2][4], accy[2][4];
#pragma unroll
    for (int i = 0; i < 2; ++i)
#pragma unroll
        for (int j = 0; j < 4; ++j) {
            accx[i][j] = (f32x4){0.f, 0.f, 0.f, 0.f};
            accy[i][j] = (f32x4){0.f, 0.f, 0.f, 0.f};
        }

    // --- GEMM1 (x and y share the W1 stream)
    for (int kk = 0; kk < CIN / 32; ++kk) {
        bf16x8 w[4];
#pragma unroll
        for (int j = 0; j < 4; ++j) {
            int cc = col0 + j * 16 + l15;
            w[j] = *reinterpret_cast<const bf16x8*>(W1b + (size_t)cc * CIN + kk * 32 + l4 * 8);
        }
#pragma unroll
        for (int i = 0; i < 2; ++i) {
            bf16x8 ax = *reinterpret_cast<const bf16x8*>(U + AX_OFF + (aoff[i] ^ (unsigned)(kk << 6)));
            bf16x8 ay = *reinterpret_cast<const bf16x8*>(U + AY_OFF + (aoff[i] ^ (unsigned)(kk << 6)));
#pragma unroll
            for (int j = 0; j < 4; ++j) {
                accx[i][j] = __builtin_amdgcn_mfma_f32_16x16x32_bf16(ax, w[j], accx[i][j], 0, 0, 0);
                accy[i][j] = __builtin_amdgcn_mfma_f32_16x16x32_bf16(ay, w[j], accy[i][j], 0, 0, 0);
            }
        }
    }
    __syncthreads();                     // all A reads done (H clobbers A)

    // --- write H1 = acc + b1 (bf16, swizzled) for both pipelines
#pragma unroll
    for (int i = 0; i < 2; ++i)
#pragma unroll
        for (int j = 0; j < 4; ++j) {
            unsigned colb = (unsigned)((col0 + j * 16 + l15) * 2);
#pragma unroll
            for (int r2 = 0; r2 < 4; ++r2) {
                int r = i * 16 + l4 * 4 + r2;
                unsigned off = (unsigned)(r * (HID * 2)) + (colb ^ ((unsigned)((r & 15) << 4)));
                *reinterpret_cast<bf16_t*>(U + HX_OFF + off) = (bf16_t)(accx[i][j][r2] + bias1[j]);
                *reinterpret_cast<bf16_t*>(U + HY_OFF + off) = (bf16_t)(accy[i][j][r2] + bias1[j]);
            }
        }
    __syncthreads();                     // H(x), H(y) ready

#pragma unroll
    for (int i = 0; i < 2; ++i)
#pragma unroll
        for (int j = 0; j < 4; ++j) {
            accx[i][j] = (f32x4){0.f, 0.f, 0.f, 0.f};
            accy[i][j] = (f32x4){0.f, 0.f, 0.f, 0.f};
        }

    // --- GEMM2 (x and y share the W2 stream)
    for (int kk = 0; kk < HID / 32; ++kk) {
        bf16x8 w[4];
#pragma unroll
        for (int j = 0; j < 4; ++j) {
            int cc = col0 + j * 16 + l15;
            w[j] = *reinterpret_cast<const bf16x8*>(W2b + (size_t)cc * HID + kk * 32 + l4 * 8);
        }
#pragma unroll
        for (int i = 0; i < 2; ++i) {
            bf16x8 ax = *reinterpret_cast<const bf16x8*>(U + HX_OFF + (hoff[i] ^ (unsigned)(kk << 6)));
            bf16x8 ay = *reinterpret_cast<const bf16x8*>(U + HY_OFF + (hoff[i] ^ (unsigned)(kk << 6)));
#pragma unroll
            for (int j = 0; j < 4; ++j) {
                accx[i][j] = __builtin_amdgcn_mfma_f32_16x16x32_bf16(ax, w[j], accx[i][j], 0, 0, 0);
                accy[i][j] = __builtin_amdgcn_mfma_f32_16x16x32_bf16(ay, w[j], accy[i][j], 0, 0, 0);
            }
        }
    }

    // --- product + reduce over the tile's 32 rows (register-only)
    float colsum[4] = {0.f, 0.f, 0.f, 0.f};
#pragma unroll
    for (int i = 0; i < 2; ++i)
#pragma unroll
        for (int j = 0; j < 4; ++j)
#pragma unroll
            for (int r2 = 0; r2 < 4; ++r2) {
                float tx = fast_tanh(accx[i][j][r2] + bias2[j]);
                float ty = fast_tanh(accy[i][j][r2] + bias2[j]);
                colsum[j] += tx * ty;
            }
#pragma unroll
    for (int j = 0; j < 4; ++j) {
        colsum[j] += __shfl_xor(colsum[j], 16);
        colsum[j] += __shfl_xor(colsum[j], 32);
    }
    if (lane < 16) {
#pragma unroll
        for (int j = 0; j < 4; ++j)
            partial[(size_t)blk * HID + col0 + j * 16 + lane] = colsum[j];
    }
}

// ---------------------------------------------------------------------------
// Kernel 3: sum the 64 l-tile partials per batch -> out[B][HID]
// ---------------------------------------------------------------------------
__global__ void reduce_kernel(const float* __restrict__ partial, float* __restrict__ out)
{
    int b = blockIdx.x;
    int g = threadIdx.x;             // 512 threads
    float s = 0.f;
#pragma unroll
    for (int t = 0; t < NLT; ++t)
        s += partial[((size_t)(b * NLT + t)) * HID + g];
    out[b * HID + g] = s;
}

extern "C" void kernel_launch(void* const* d_in, const int* in_sizes, int n_in,
                              void* d_out, int out_size, void* d_ws, size_t ws_size,
                              hipStream_t stream)
{
    const float* x  = (const float*)d_in[0];
    const float* y  = (const float*)d_in[1];
    const float* W1 = (const float*)d_in[2];
    const float* b1 = (const float*)d_in[3];
    const float* W2 = (const float*)d_in[4];
    const float* b2 = (const float*)d_in[5];
    float* out = (float*)d_out;

    char* ws = (char*)d_ws;
    bf16_t* W1b    = (bf16_t*)ws;                    // 256 KB
    bf16_t* W2b    = (bf16_t*)(ws + (256 << 10));    // 512 KB
    float*  partial = (float*)(ws + (768 << 10));    // 4 MB (2048 blocks x 512)

    hipLaunchKernelGGL(cast_weights_kernel, dim3(1024), dim3(256), 0, stream, W1, W2, W1b, W2b);
    hipLaunchKernelGGL(fused_proj_kernel, dim3(B_ * NLT), dim3(512), 0, stream,
                       x, y, W1b, b1, W2b, b2, partial);
    hipLaunchKernelGGL(reduce_kernel, dim3(B_), dim3(512), 0, stream, partial, out);
}